// Round 1
// baseline (89.114 us; speedup 1.0000x reference)
//
#include <hip/hip_runtime.h>

typedef float f32x4 __attribute__((ext_vector_type(4)));

// LIF forward scan: one thread owns 4 neuron columns, loops over T.
// Memory-bound streaming: 256 MiB in + 256 MiB out -> roofline ~81us @6.3TB/s.
__global__ __launch_bounds__(256) void lif_fwd_kernel(
    const f32x4* __restrict__ x,      // [T, BN/4]
    const f32x4* __restrict__ v0,     // [BN/4]
    const float* __restrict__ decay_p,
    const float* __restrict__ thr_p,
    f32x4* __restrict__ out,          // [T, BN/4]
    int bn4, int T)
{
    int i = blockIdx.x * blockDim.x + threadIdx.x;
    if (i >= bn4) return;

    const float decay = decay_p[0];
    const float thr   = thr_p[0];

    f32x4 v = v0[i];

    size_t idx = (size_t)i;
    #pragma unroll 4
    for (int t = 0; t < T; ++t, idx += (size_t)bn4) {
        f32x4 xt = __builtin_nontemporal_load(&x[idx]);
        f32x4 s;
        v.x = decay * v.x + xt.x; s.x = (v.x >= thr) ? 1.0f : 0.0f; v.x -= s.x * thr;
        v.y = decay * v.y + xt.y; s.y = (v.y >= thr) ? 1.0f : 0.0f; v.y -= s.y * thr;
        v.z = decay * v.z + xt.z; s.z = (v.z >= thr) ? 1.0f : 0.0f; v.z -= s.z * thr;
        v.w = decay * v.w + xt.w; s.w = (v.w >= thr) ? 1.0f : 0.0f; v.w -= s.w * thr;
        __builtin_nontemporal_store(s, &out[idx]);
    }
}

extern "C" void kernel_launch(void* const* d_in, const int* in_sizes, int n_in,
                              void* d_out, int out_size, void* d_ws, size_t ws_size,
                              hipStream_t stream) {
    // setup_inputs order: x_seq [T,B,N] f32, v0 [B*N] f32, decay, threshold, alpha
    const f32x4* x     = (const f32x4*)d_in[0];
    const f32x4* v0    = (const f32x4*)d_in[1];
    const float* decay = (const float*)d_in[2];
    const float* thr   = (const float*)d_in[3];
    // alpha (d_in[4]) is backward-only; unused in forward.

    f32x4* out = (f32x4*)d_out;

    const int bn  = in_sizes[1];          // B*N = 262144
    const int bn4 = bn / 4;               // 65536 float4 columns
    const int T   = in_sizes[0] / bn;     // 256

    const int block = 256;
    const int grid  = (bn4 + block - 1) / block;

    lif_fwd_kernel<<<grid, block, 0, stream>>>(x, v0, decay, thr, out, bn4, T);
}